// Round 9
// baseline (184.960 us; speedup 1.0000x reference)
//
#include <hip/hip_runtime.h>

// LocallyConnectedGC: out[bt, m] = sum_n x[bt, n] * (S*W)[n, m] + b[m]
// S = band mask of half-width 4 on a 208-node ring -> 9 weights per column.
//
// R8 = R5 structure (best so far: 47.75us) + three fixes:
//  - Band built cooperatively in LDS once per block (R5 spent 24 float4
//    global reads PER THREAD on W/S: ~160 MB of L2 setup traffic).
//  - Grid 2048 (16 rows/wave), __launch_bounds__(256,5) caps VGPR at ~102
//    -> ~20 waves/CU resident (R5: 16).
//  - Pipeline pair-loop bounds RUNTIME-derived (gridDim-based). R7 proved
//    static bounds let the compiler unroll + sink loads (VGPR 96 -> 56,
//    dur +34%). Runtime bounds force buffers live across the back-edge.

#define NN   208
#define NC   52      // NN/4 float4 chunks per row
#define HW   4
#define BAND 9
#define THREADS 256
#define WPB  4       // waves per block
#define RPB  4       // rows per pipeline batch
#define IPT  16      // rows per wave (grid derived from this on host)

typedef float vfloat4 __attribute__((ext_vector_type(4)));

struct Buf { float4 a[RPB], c[RPB], e[RPB]; };

__device__ __forceinline__ void load_batch(Buf& B, const float* __restrict__ x,
                                           long long row0,
                                           int cm, int cc, int cp) {
    #pragma unroll
    for (int r = 0; r < RPB; ++r) {
        const float4* __restrict__ xrow =
            reinterpret_cast<const float4*>(x + (row0 + r) * NN);
        B.a[r] = xrow[cm];
        B.c[r] = xrow[cc];
        B.e[r] = xrow[cp];
    }
}

__device__ __forceinline__ void compute_store(const Buf& B, const float4* bnd,
                                              float4 bias4, float* __restrict__ out,
                                              long long row0, int lane) {
    #pragma unroll
    for (int r = 0; r < RPB; ++r) {
        const float xv[12] = {B.a[r].x, B.a[r].y, B.a[r].z, B.a[r].w,
                              B.c[r].x, B.c[r].y, B.c[r].z, B.c[r].w,
                              B.e[r].x, B.e[r].y, B.e[r].z, B.e[r].w};
        float4 acc = bias4;
        #pragma unroll
        for (int d = 0; d < BAND; ++d) {
            acc.x = fmaf(bnd[d].x, xv[0 + d], acc.x);
            acc.y = fmaf(bnd[d].y, xv[1 + d], acc.y);
            acc.z = fmaf(bnd[d].z, xv[2 + d], acc.z);
            acc.w = fmaf(bnd[d].w, xv[3 + d], acc.w);
        }
        vfloat4 av = {acc.x, acc.y, acc.z, acc.w};
        __builtin_nontemporal_store(
            av, reinterpret_cast<vfloat4*>(out + (row0 + r) * NN + lane * 4));
    }
}

__global__ __launch_bounds__(THREADS, 5) void lcgc_kernel(
    const float* __restrict__ x,
    const float* __restrict__ W,
    const float* __restrict__ b,
    const float* __restrict__ S,
    float* __restrict__ out,
    int total_rows)
{
    __shared__ float sBand[BAND * NN];
    __shared__ float sBias[NN];

    // Cooperative band build: coalesced over m for each d; W/S stay L2-hot.
    for (int i = threadIdx.x; i < BAND * NN; i += THREADS) {
        int d = i / NN;
        int m = i - d * NN;
        int n = m + d - HW;
        if (n < 0) n += NN;
        else if (n >= NN) n -= NN;
        sBand[i] = W[n * NN + m] * S[n * NN + m];
    }
    if (threadIdx.x < NN) sBias[threadIdx.x] = b[threadIdx.x];
    __syncthreads();

    const int lane = threadIdx.x & 63;
    const int wave = threadIdx.x >> 6;
    if (lane >= NC) return;   // after the barrier: safe

    // Per-lane constants for output cols 4*lane..4*lane+3.
    float4 bnd[BAND];
    #pragma unroll
    for (int d = 0; d < BAND; ++d)
        bnd[d] = *reinterpret_cast<const float4*>(&sBand[d * NN + lane * 4]);
    const float4 bias4 = *reinterpret_cast<const float4*>(&sBias[lane * 4]);

    const int cm = (lane == 0)      ? NC - 1 : lane - 1;
    const int cp = (lane == NC - 1) ? 0      : lane + 1;

    // ---- 2-deep pipeline, RUNTIME loop bounds (keeps buffers live) ----
    const long long gwave = (long long)blockIdx.x * WPB + wave;
    const long long waves_total = (long long)gridDim.x * WPB;
    const long long rows_per_wave = total_rows / waves_total;   // 16 (runtime)
    const long long nb = rows_per_wave / RPB;                   // 4  (runtime)
    const long long npairs = nb / 2;                            // 2  (runtime)

    long long rowA = gwave * rows_per_wave;
    Buf A, B;
    load_batch(A, x, rowA, cm, lane, cp);

    for (long long k = 0; k < npairs - 1; ++k) {
        const long long rowB = rowA + RPB;
        load_batch(B, x, rowB, cm, lane, cp);
        __builtin_amdgcn_sched_group_barrier(0x20, 12, 0);  // 12 VMEM_READ first
        compute_store(A, bnd, bias4, out, rowA, lane);

        const long long rowA2 = rowA + 2 * RPB;
        load_batch(A, x, rowA2, cm, lane, cp);
        __builtin_amdgcn_sched_group_barrier(0x20, 12, 0);
        compute_store(B, bnd, bias4, out, rowB, lane);
        rowA = rowA2;
    }
    // Epilogue pair.
    {
        const long long rowB = rowA + RPB;
        load_batch(B, x, rowB, cm, lane, cp);
        __builtin_amdgcn_sched_group_barrier(0x20, 12, 0);
        compute_store(A, bnd, bias4, out, rowA, lane);
        compute_store(B, bnd, bias4, out, rowB, lane);
        rowA = rowB + RPB;
    }
    // Remainder rows if nb was odd (not hit at the bench shape).
    for (long long rr = rowA; rr < (gwave + 1) * rows_per_wave; rr += RPB) {
        load_batch(A, x, rr, cm, lane, cp);
        compute_store(A, bnd, bias4, out, rr, lane);
    }
}

extern "C" void kernel_launch(void* const* d_in, const int* in_sizes, int n_in,
                              void* d_out, int out_size, void* d_ws, size_t ws_size,
                              hipStream_t stream) {
    const float* x = (const float*)d_in[0];
    const float* W = (const float*)d_in[1];
    const float* b = (const float*)d_in[2];
    const float* S = (const float*)d_in[3];
    float* out = (float*)d_out;

    const int total_rows = in_sizes[0] / NN;           // 131072
    const int nblocks = total_rows / (IPT * WPB);      // 2048

    lcgc_kernel<<<dim3(nblocks), dim3(THREADS), 0, stream>>>(
        x, W, b, S, out, total_rows);
}

// Round 10
// 59.861 us; speedup vs baseline: 3.0898x; 3.0898x over previous
//
#include <hip/hip_runtime.h>

// LocallyConnectedGC: out[bt, m] = sum_n x[bt, n] * (S*W)[n, m] + b[m]
// S = band mask of half-width 4 on a 208-node ring -> 9 weights per column.
//
// R9 = R5 (best: 47.75us, VGPR 96, 12-deep MLP alive) + ONE change:
//   grid 1024 -> 2048 blocks (8 rows/wave, nb=4, npairs=2). Runtime loop
//   bounds retained -> pipeline survives codegen (R7/R8 proved static
//   bounds / launch_bounds kill it: VGPR 96 -> 56/48, scratch spills).
// R8 post-mortem: never add __launch_bounds__ min-waves to this kernel.

#define NN   208
#define NC   52      // NN/4 float4 chunks per row
#define HW   4
#define BAND 9
#define THREADS 256
#define WPB  4       // waves per block
#define RPB  4       // rows per batch (per wave pipeline stage)
#define NBLK 2048

typedef float vfloat4 __attribute__((ext_vector_type(4)));

struct Buf { float4 a[RPB], c[RPB], e[RPB]; };

__device__ __forceinline__ void load_batch(Buf& B, const float* __restrict__ x,
                                           long long row0, int cm, int cc, int cp) {
    #pragma unroll
    for (int r = 0; r < RPB; ++r) {
        const float4* __restrict__ xrow =
            reinterpret_cast<const float4*>(x + (row0 + r) * NN);
        B.a[r] = xrow[cm];
        B.c[r] = xrow[cc];
        B.e[r] = xrow[cp];
    }
}

__device__ __forceinline__ void compute_store(const Buf& B, const float4* bnd,
                                              float4 bias4, float* __restrict__ out,
                                              long long row0, int lane) {
    #pragma unroll
    for (int r = 0; r < RPB; ++r) {
        const float xv[12] = {B.a[r].x, B.a[r].y, B.a[r].z, B.a[r].w,
                              B.c[r].x, B.c[r].y, B.c[r].z, B.c[r].w,
                              B.e[r].x, B.e[r].y, B.e[r].z, B.e[r].w};
        float4 acc = bias4;
        #pragma unroll
        for (int d = 0; d < BAND; ++d) {
            acc.x = fmaf(bnd[d].x, xv[0 + d], acc.x);
            acc.y = fmaf(bnd[d].y, xv[1 + d], acc.y);
            acc.z = fmaf(bnd[d].z, xv[2 + d], acc.z);
            acc.w = fmaf(bnd[d].w, xv[3 + d], acc.w);
        }
        vfloat4 av = {acc.x, acc.y, acc.z, acc.w};
        __builtin_nontemporal_store(
            av, reinterpret_cast<vfloat4*>(out + (row0 + r) * NN + lane * 4));
    }
}

__global__ __launch_bounds__(THREADS) void lcgc_kernel(
    const float* __restrict__ x,
    const float* __restrict__ W,
    const float* __restrict__ b,
    const float* __restrict__ S,
    float* __restrict__ out,
    int total_rows)
{
    const int lane = threadIdx.x & 63;
    const int wave = threadIdx.x >> 6;
    if (lane >= NC) return;

    // ---- Per-lane band: bnd[d] for output cols 4*lane..4*lane+3 ----
    // Needs (S*W)[n][m] for n = 4*lane-4 .. 4*lane+7 (12 rows, 4 cols each).
    float4 w4[BAND + 3], s4[BAND + 3];
    #pragma unroll
    for (int r = 0; r < BAND + 3; ++r) {
        int n = 4 * lane - HW + r;
        if (n < 0) n += NN;
        else if (n >= NN) n -= NN;
        w4[r] = *reinterpret_cast<const float4*>(&W[n * NN + lane * 4]);
        s4[r] = *reinterpret_cast<const float4*>(&S[n * NN + lane * 4]);
    }
    float4 bnd[BAND];
    #pragma unroll
    for (int d = 0; d < BAND; ++d) {
        bnd[d].x = w4[d + 0].x * s4[d + 0].x;   // m=4l+0: n-row = d+0
        bnd[d].y = w4[d + 1].y * s4[d + 1].y;   // m=4l+1: n-row = d+1
        bnd[d].z = w4[d + 2].z * s4[d + 2].z;   // m=4l+2: n-row = d+2
        bnd[d].w = w4[d + 3].w * s4[d + 3].w;   // m=4l+3: n-row = d+3
    }
    const float4 bias4 = *reinterpret_cast<const float4*>(&b[lane * 4]);

    const int cm = (lane == 0)      ? NC - 1 : lane - 1;
    const int cp = (lane == NC - 1) ? 0      : lane + 1;

    // ---- Persistent pipeline over 4-row batches (runtime bounds!) ----
    const long long batches_total = total_rows / RPB;           // 32768
    const long long waves_total   = (long long)gridDim.x * WPB; // 8192
    const long long gwave = (long long)blockIdx.x * WPB + wave;
    const long long nb = batches_total / waves_total;           // 4 (even)

    long long bt = gwave;
    Buf A, B;
    load_batch(A, x, bt * RPB, cm, lane, cp);

    const long long npairs = nb / 2;                            // 2
    for (long long k = 0; k < npairs - 1; ++k) {
        const long long btB = bt + waves_total;
        load_batch(B, x, btB * RPB, cm, lane, cp);
        __builtin_amdgcn_sched_group_barrier(0x20, 12, 0);  // 12 VMEM_READ first
        compute_store(A, bnd, bias4, out, bt * RPB, lane);

        const long long btA = bt + 2 * waves_total;
        load_batch(A, x, btA * RPB, cm, lane, cp);
        __builtin_amdgcn_sched_group_barrier(0x20, 12, 0);
        compute_store(B, bnd, bias4, out, btB * RPB, lane);
        bt = btA;
    }
    // Epilogue pair (no further prefetch).
    {
        const long long btB = bt + waves_total;
        load_batch(B, x, btB * RPB, cm, lane, cp);
        __builtin_amdgcn_sched_group_barrier(0x20, 12, 0);
        compute_store(A, bnd, bias4, out, bt * RPB, lane);
        compute_store(B, bnd, bias4, out, btB * RPB, lane);
        bt = btB + waves_total;
    }
    // Remainder batches, if grid doesn't divide evenly (not hit at 131072).
    for (long long bb = nb * waves_total + gwave; bb < batches_total;
         bb += waves_total) {
        load_batch(A, x, bb * RPB, cm, lane, cp);
        compute_store(A, bnd, bias4, out, bb * RPB, lane);
    }
}

extern "C" void kernel_launch(void* const* d_in, const int* in_sizes, int n_in,
                              void* d_out, int out_size, void* d_ws, size_t ws_size,
                              hipStream_t stream) {
    const float* x = (const float*)d_in[0];
    const float* W = (const float*)d_in[1];
    const float* b = (const float*)d_in[2];
    const float* S = (const float*)d_in[3];
    float* out = (float*)d_out;

    const int total_rows = in_sizes[0] / NN;   // 131072

    lcgc_kernel<<<dim3(NBLK), dim3(THREADS), 0, stream>>>(
        x, W, b, S, out, total_rows);
}

// Round 11
// 56.807 us; speedup vs baseline: 3.2559x; 1.0538x over previous
//
#include <hip/hip_runtime.h>

// LocallyConnectedGC: out[bt, m] = sum_n x[bt, n] * (S*W)[n, m] + b[m]
// S = band mask of half-width 4 on a 208-node ring -> 9 weights per column.
//
// R10 = full-lane flat-chunk mapping (R7's locality) + R5's runtime-bounded
// pipeline skeleton (the part R7 accidentally dropped).
//  - Thread owns fixed chunk c = flat%52 and 16 CONTIGUOUS rows starting at
//    (flat/52)*16. All 64 lanes active (R5 idles 12/64 = 19%).
//  - Per 4-row batch: 12 float4 loads clustered in 3.3 KB (base+imm offsets).
//  - Pair-loop bounds RUNTIME-derived -> buffers stay live across the
//    back-edge (R5/R9: VGPR 96 alive; R7 straight-line: VGPR 56 dead).
//  - sched_group_barrier(VMEM_READ,12) before each compute keeps 12 loads
//    in flight under 144 FMAs. Nontemporal float4 stores.

#define NN   208
#define NC   52      // NN/4 float4 chunks per row
#define HW   4
#define BAND 9
#define THREADS 256
#define NBLK 1664    // 425984 threads = 52 chunks * 8192 row-groups
#define RPB  4       // rows per pipeline batch

typedef float vfloat4 __attribute__((ext_vector_type(4)));

struct Buf { float4 a[RPB], c[RPB], e[RPB]; };

__device__ __forceinline__ void load_batch(Buf& B, const float* __restrict__ x,
                                           long long row0,
                                           int cm, int cc, int cp) {
    #pragma unroll
    for (int r = 0; r < RPB; ++r) {
        const float4* __restrict__ xrow =
            reinterpret_cast<const float4*>(x + (row0 + r) * NN);
        B.a[r] = xrow[cm];
        B.c[r] = xrow[cc];
        B.e[r] = xrow[cp];
    }
}

__device__ __forceinline__ void compute_store(const Buf& B, const float4* bnd,
                                              float4 bias4, float* __restrict__ out,
                                              long long row0, int c) {
    #pragma unroll
    for (int r = 0; r < RPB; ++r) {
        const float xv[12] = {B.a[r].x, B.a[r].y, B.a[r].z, B.a[r].w,
                              B.c[r].x, B.c[r].y, B.c[r].z, B.c[r].w,
                              B.e[r].x, B.e[r].y, B.e[r].z, B.e[r].w};
        float4 acc = bias4;
        #pragma unroll
        for (int d = 0; d < BAND; ++d) {
            acc.x = fmaf(bnd[d].x, xv[0 + d], acc.x);
            acc.y = fmaf(bnd[d].y, xv[1 + d], acc.y);
            acc.z = fmaf(bnd[d].z, xv[2 + d], acc.z);
            acc.w = fmaf(bnd[d].w, xv[3 + d], acc.w);
        }
        vfloat4 av = {acc.x, acc.y, acc.z, acc.w};
        __builtin_nontemporal_store(
            av, reinterpret_cast<vfloat4*>(out + (row0 + r) * NN + c * 4));
    }
}

__global__ __launch_bounds__(THREADS) void lcgc_kernel(
    const float* __restrict__ x,
    const float* __restrict__ W,
    const float* __restrict__ b,
    const float* __restrict__ S,
    float* __restrict__ out,
    int total_rows)
{
    const long long flat = (long long)blockIdx.x * THREADS + threadIdx.x;
    const long long total_threads = (long long)gridDim.x * THREADS;
    const int c = (int)(flat % NC);

    // Runtime-derived per-thread row range (16 contiguous rows at bench shape).
    const long long rows_per_thread =
        ((long long)total_rows * NC) / total_threads;        // 16 (runtime)
    const long long r0 = (flat / NC) * rows_per_thread;

    // ---- Per-thread band: bnd[d] for output cols 4c..4c+3 ----
    float4 w4[BAND + 3], s4[BAND + 3];
    #pragma unroll
    for (int r = 0; r < BAND + 3; ++r) {
        int n = 4 * c - HW + r;
        if (n < 0) n += NN;
        else if (n >= NN) n -= NN;
        w4[r] = *reinterpret_cast<const float4*>(&W[n * NN + c * 4]);
        s4[r] = *reinterpret_cast<const float4*>(&S[n * NN + c * 4]);
    }
    float4 bnd[BAND];
    #pragma unroll
    for (int d = 0; d < BAND; ++d) {
        bnd[d].x = w4[d + 0].x * s4[d + 0].x;   // m=4c+0: n-row = d+0
        bnd[d].y = w4[d + 1].y * s4[d + 1].y;   // m=4c+1: n-row = d+1
        bnd[d].z = w4[d + 2].z * s4[d + 2].z;   // m=4c+2: n-row = d+2
        bnd[d].w = w4[d + 3].w * s4[d + 3].w;   // m=4c+3: n-row = d+3
    }
    const float4 bias4 = *reinterpret_cast<const float4*>(&b[c * 4]);

    const int cm = (c == 0)      ? NC - 1 : c - 1;
    const int cp = (c == NC - 1) ? 0      : c + 1;

    // ---- 2-deep pipeline, RUNTIME loop bounds (R5 skeleton verbatim) ----
    const long long nb = rows_per_thread / RPB;              // 4 (runtime)
    const long long npairs = nb / 2;                         // 2 (runtime)

    long long rowA = r0;
    Buf A, B;
    load_batch(A, x, rowA, cm, c, cp);

    for (long long k = 0; k < npairs - 1; ++k) {
        const long long rowB = rowA + RPB;
        load_batch(B, x, rowB, cm, c, cp);
        __builtin_amdgcn_sched_group_barrier(0x20, 12, 0);  // 12 VMEM_READ first
        compute_store(A, bnd, bias4, out, rowA, c);

        const long long rowA2 = rowA + 2 * RPB;
        load_batch(A, x, rowA2, cm, c, cp);
        __builtin_amdgcn_sched_group_barrier(0x20, 12, 0);
        compute_store(B, bnd, bias4, out, rowB, c);
        rowA = rowA2;
    }
    // Epilogue pair (no further prefetch).
    {
        const long long rowB = rowA + RPB;
        load_batch(B, x, rowB, cm, c, cp);
        __builtin_amdgcn_sched_group_barrier(0x20, 12, 0);
        compute_store(A, bnd, bias4, out, rowA, c);
        compute_store(B, bnd, bias4, out, rowB, c);
        rowA = rowB + RPB;
    }
    // Remainder batches if nb was odd (not hit at bench shape).
    for (long long rr = rowA; rr < r0 + rows_per_thread; rr += RPB) {
        load_batch(A, x, rr, cm, c, cp);
        compute_store(A, bnd, bias4, out, rr, c);
    }
}

extern "C" void kernel_launch(void* const* d_in, const int* in_sizes, int n_in,
                              void* d_out, int out_size, void* d_ws, size_t ws_size,
                              hipStream_t stream) {
    const float* x = (const float*)d_in[0];
    const float* W = (const float*)d_in[1];
    const float* b = (const float*)d_in[2];
    const float* S = (const float*)d_in[3];
    float* out = (float*)d_out;

    const int total_rows = in_sizes[0] / NN;   // 131072

    lcgc_kernel<<<dim3(NBLK), dim3(THREADS), 0, stream>>>(
        x, W, b, S, out, total_rows);
}

// Round 12
// 43.274 us; speedup vs baseline: 4.2742x; 1.3127x over previous
//
#include <hip/hip_runtime.h>

// LocallyConnectedGC: out[bt, m] = sum_n x[bt, n] * (S*W)[n, m] + b[m]
// S = band mask, half-width 4, ring of 208 -> 9 weights per output column.
//
// R11: LDS-staged tiles via global_load_lds + counted-vmcnt double buffer.
//  R5..R10 all plateaued at ~19% occupancy / ~3.4 TB/s: register pipelines
//  cap residency (VGPR 96+) AND can't hold enough loads in flight.
//  global_load_lds gives loads-in-flight with ZERO VGPR cost.
//  - Block = 832 threads (13 waves) = one 16x208 tile; thread t stages
//    float4 #t of the tile: LDS dest = wave_base + lane*16 (linear, legal),
//    global src = tile_base + t*16 (coalesced). 1 load/thread/tile.
//  - 2-deep tile pipeline: stage k+1, s_waitcnt vmcnt(1) (keep k+1 in
//    flight!), raw s_barrier, compute k, raw s_barrier. NO __syncthreads
//    in the loop (it drains vmcnt to 0 and kills the prefetch).
//  - Thread owns column-chunk c = t%52, row rg = t/52: 3 x-float4 + 9
//    band-float4 from LDS, 36 FMA, 1 nt store. VGPR ~55 -> 26 waves/CU.

#define NN   208
#define NC   52          // NN/4 float4 chunks per row
#define HW   4
#define BAND 9
#define TR   16          // rows per tile
#define THREADS 832      // = TR*NC threads: 13 waves
#define NBLK 512         // 2 blocks/CU * 256 CU
#define TILE_F  (TR * NN)     // 3328 floats per tile
#define TILE_F4 (TILE_F / 4)  // 832 float4 per tile = THREADS

typedef float vfloat4 __attribute__((ext_vector_type(4)));

__global__ __launch_bounds__(THREADS) void lcgc_kernel(
    const float* __restrict__ x,
    const float* __restrict__ W,
    const float* __restrict__ b,
    const float* __restrict__ S,
    float* __restrict__ out,
    int total_rows)
{
    __shared__ float sX[2][TILE_F];      // 26.6 KB double-buffered x tile
    __shared__ float sBand[BAND * NN];   // 7.5 KB masked weight band

    const int tid = threadIdx.x;

    // One-time cooperative band build (coalesced over m; W/S L2-hot).
    for (int i = tid; i < BAND * NN; i += THREADS) {
        int d = i / NN;
        int m = i - d * NN;
        int n = m + d - HW;
        if (n < 0) n += NN;
        else if (n >= NN) n -= NN;
        sBand[i] = W[n * NN + m] * S[n * NN + m];
    }
    __syncthreads();   // before any staging: full drain here is fine

    const int c    = tid % NC;           // fixed column chunk
    const int rg   = tid / NC;           // row within tile, 0..15
    const int wave = tid >> 6;

    const float4 bias4 = *reinterpret_cast<const float4*>(&b[c * 4]);
    const int cm = (c == 0)      ? NC - 1 : c - 1;
    const int cp = (c == NC - 1) ? 0      : c + 1;

    const long long ntiles_total = total_rows / TR;          // 8192
    const long long nt = ntiles_total / gridDim.x;           // 16 (runtime)
    const long long t0 = (long long)blockIdx.x * nt;

    // Wave-uniform LDS bases for staging (HW writes base + lane*16).
    float* const ldst0 = &sX[0][wave * 256];   // wave*64 float4 = wave*256 floats
    float* const ldst1 = &sX[1][wave * 256];

    #define STAGE(kt, bi)                                                     \
        do {                                                                  \
            const float* gsrc = x + (t0 + (kt)) * TILE_F + (long long)tid * 4;\
            __builtin_amdgcn_global_load_lds(                                 \
                (const __attribute__((address_space(1))) void*)(gsrc),        \
                (__attribute__((address_space(3))) void*)((bi) ? ldst1 : ldst0),\
                16, 0, 0);                                                    \
        } while (0)

    #define COMPUTE(kt, bi)                                                   \
        do {                                                                  \
            const float4* xr4 =                                               \
                reinterpret_cast<const float4*>(&sX[(bi)][rg * NN]);          \
            const float4 a = xr4[cm];                                         \
            const float4 m4 = xr4[c];                                         \
            const float4 e = xr4[cp];                                         \
            const float xv[12] = {a.x, a.y, a.z, a.w,                         \
                                  m4.x, m4.y, m4.z, m4.w,                     \
                                  e.x, e.y, e.z, e.w};                        \
            float4 acc = bias4;                                               \
            const float4* band4 = reinterpret_cast<const float4*>(sBand);     \
            _Pragma("unroll")                                                 \
            for (int d = 0; d < BAND; ++d) {                                  \
                const float4 bd = band4[d * NC + c];                          \
                acc.x = fmaf(bd.x, xv[0 + d], acc.x);                         \
                acc.y = fmaf(bd.y, xv[1 + d], acc.y);                         \
                acc.z = fmaf(bd.z, xv[2 + d], acc.z);                         \
                acc.w = fmaf(bd.w, xv[3 + d], acc.w);                         \
            }                                                                 \
            vfloat4 av = {acc.x, acc.y, acc.z, acc.w};                        \
            __builtin_nontemporal_store(av, reinterpret_cast<vfloat4*>(       \
                out + (t0 + (kt)) * TILE_F + rg * NN + c * 4));               \
        } while (0)

    // Prologue: stage tile 0 into buffer 0.
    STAGE(0, 0);

    for (long long k = 0; k < nt - 1; ++k) {
        STAGE(k + 1, (int)((k + 1) & 1));
        // Wait for tile k's loads (in-order count: leaves the newest,
        // tile k+1's, in flight). Also drains our k-1 store — harmless.
        asm volatile("s_waitcnt vmcnt(1)" ::: "memory");
        __builtin_amdgcn_sched_barrier(0);
        __builtin_amdgcn_s_barrier();      // all waves' tile-k data visible
        COMPUTE(k, (int)(k & 1));
        asm volatile("" ::: "memory");
        __builtin_amdgcn_s_barrier();      // everyone done reading buf k&1
    }
    // Epilogue: last tile, nothing left to prefetch.
    asm volatile("s_waitcnt vmcnt(0)" ::: "memory");
    __builtin_amdgcn_sched_barrier(0);
    __builtin_amdgcn_s_barrier();
    COMPUTE(nt - 1, (int)((nt - 1) & 1));

    #undef STAGE
    #undef COMPUTE
}

extern "C" void kernel_launch(void* const* d_in, const int* in_sizes, int n_in,
                              void* d_out, int out_size, void* d_ws, size_t ws_size,
                              hipStream_t stream) {
    const float* x = (const float*)d_in[0];
    const float* W = (const float*)d_in[1];
    const float* b = (const float*)d_in[2];
    const float* S = (const float*)d_in[3];
    float* out = (float*)d_out;

    const int total_rows = in_sizes[0] / NN;   // 131072 = 8192 tiles of 16
    lcgc_kernel<<<dim3(NBLK), dim3(THREADS), 0, stream>>>(
        x, W, b, S, out, total_rows);
}

// Round 13
// 42.656 us; speedup vs baseline: 4.3361x; 1.0145x over previous
//
#include <hip/hip_runtime.h>

// LocallyConnectedGC: out[bt, m] = sum_n x[bt, n] * (S*W)[n, m] + b[m]
// S = band mask, half-width 4, ring of 208 -> 9 weights per output column.
//
// R12 = R11 (best: 43.27us) + ONE change: band hoisted to REGISTERS.
//  R11 re-read the 9 band float4s from LDS every tile (barriers' memory
//  clobbers block hoisting): 12 ds_read_b128/thread/tile, LDS pipe ~85%
//  busy, 6.7M bank-conflict cycles. Now: band+bias read ONCE into regs
//  before the tile loop; steady state is 3 ds_read_b128/thread/tile.
//  - Block = 832 threads (13 waves) stages one 16x208 tile/step via
//    global_load_lds (zero-VGPR loads in flight), double-buffered,
//    counted vmcnt(1) + raw s_barrier (NO __syncthreads in loop).
//  - Thread owns chunk c = tid%52, row rg = tid/52: 3 x-float4 LDS reads,
//    36 FMA, 1 nontemporal float4 store.

#define NN   208
#define NC   52          // NN/4 float4 chunks per row
#define HW   4
#define BAND 9
#define TR   16          // rows per tile
#define THREADS 832      // = TR*NC threads: 13 waves
#define NBLK 512
#define TILE_F  (TR * NN)     // 3328 floats per tile

typedef float vfloat4 __attribute__((ext_vector_type(4)));

__global__ __launch_bounds__(THREADS) void lcgc_kernel(
    const float* __restrict__ x,
    const float* __restrict__ W,
    const float* __restrict__ b,
    const float* __restrict__ S,
    float* __restrict__ out,
    int total_rows)
{
    __shared__ float sX[2][TILE_F];      // 26.6 KB double-buffered x tile
    __shared__ float sBand[BAND * NN];   // 7.5 KB masked weight band

    const int tid = threadIdx.x;

    // One-time cooperative band build (coalesced over m; W/S L2-hot).
    for (int i = tid; i < BAND * NN; i += THREADS) {
        int d = i / NN;
        int m = i - d * NN;
        int n = m + d - HW;
        if (n < 0) n += NN;
        else if (n >= NN) n -= NN;
        sBand[i] = W[n * NN + m] * S[n * NN + m];
    }
    __syncthreads();   // before any staging: full drain here is fine

    const int c    = tid % NC;           // fixed column chunk
    const int rg   = tid / NC;           // row within tile, 0..15
    const int wave = tid >> 6;

    // Hoist band + bias into registers ONCE (R11 re-read these every tile).
    float4 bnd[BAND];
    {
        const float4* band4 = reinterpret_cast<const float4*>(sBand);
        #pragma unroll
        for (int d = 0; d < BAND; ++d) bnd[d] = band4[d * NC + c];
    }
    const float4 bias4 = *reinterpret_cast<const float4*>(&b[c * 4]);

    const int cm = (c == 0)      ? NC - 1 : c - 1;
    const int cp = (c == NC - 1) ? 0      : c + 1;

    const long long ntiles_total = total_rows / TR;          // 8192
    const long long nt = ntiles_total / gridDim.x;           // 16 (runtime)
    const long long t0 = (long long)blockIdx.x * nt;

    // Wave-uniform LDS bases for staging (HW writes base + lane*16).
    float* const ldst0 = &sX[0][wave * 256];   // wave*64 float4 = wave*256 floats
    float* const ldst1 = &sX[1][wave * 256];

    #define STAGE(kt, bi)                                                     \
        do {                                                                  \
            const float* gsrc = x + (t0 + (kt)) * TILE_F + (long long)tid * 4;\
            __builtin_amdgcn_global_load_lds(                                 \
                (const __attribute__((address_space(1))) void*)(gsrc),        \
                (__attribute__((address_space(3))) void*)((bi) ? ldst1 : ldst0),\
                16, 0, 0);                                                    \
        } while (0)

    #define COMPUTE(kt, bi)                                                   \
        do {                                                                  \
            const float4* xr4 =                                               \
                reinterpret_cast<const float4*>(&sX[(bi)][rg * NN]);          \
            const float4 a = xr4[cm];                                         \
            const float4 m4 = xr4[c];                                         \
            const float4 e = xr4[cp];                                         \
            const float xv[12] = {a.x, a.y, a.z, a.w,                         \
                                  m4.x, m4.y, m4.z, m4.w,                     \
                                  e.x, e.y, e.z, e.w};                        \
            float4 acc = bias4;                                               \
            _Pragma("unroll")                                                 \
            for (int d = 0; d < BAND; ++d) {                                  \
                acc.x = fmaf(bnd[d].x, xv[0 + d], acc.x);                     \
                acc.y = fmaf(bnd[d].y, xv[1 + d], acc.y);                     \
                acc.z = fmaf(bnd[d].z, xv[2 + d], acc.z);                     \
                acc.w = fmaf(bnd[d].w, xv[3 + d], acc.w);                     \
            }                                                                 \
            vfloat4 av = {acc.x, acc.y, acc.z, acc.w};                        \
            __builtin_nontemporal_store(av, reinterpret_cast<vfloat4*>(       \
                out + (t0 + (kt)) * TILE_F + rg * NN + c * 4));               \
        } while (0)

    // Prologue: stage tile 0 into buffer 0.
    STAGE(0, 0);

    for (long long k = 0; k < nt - 1; ++k) {
        STAGE(k + 1, (int)((k + 1) & 1));
        // Wait for tile k's loads; leaves tile k+1's staging in flight.
        asm volatile("s_waitcnt vmcnt(1)" ::: "memory");
        __builtin_amdgcn_sched_barrier(0);
        __builtin_amdgcn_s_barrier();      // all waves' tile-k data visible
        COMPUTE(k, (int)(k & 1));
        asm volatile("" ::: "memory");
        __builtin_amdgcn_s_barrier();      // everyone done reading buf k&1
    }
    // Epilogue: last tile, nothing left to prefetch.
    asm volatile("s_waitcnt vmcnt(0)" ::: "memory");
    __builtin_amdgcn_sched_barrier(0);
    __builtin_amdgcn_s_barrier();
    COMPUTE(nt - 1, (int)((nt - 1) & 1));

    #undef STAGE
    #undef COMPUTE
}

extern "C" void kernel_launch(void* const* d_in, const int* in_sizes, int n_in,
                              void* d_out, int out_size, void* d_ws, size_t ws_size,
                              hipStream_t stream) {
    const float* x = (const float*)d_in[0];
    const float* W = (const float*)d_in[1];
    const float* b = (const float*)d_in[2];
    const float* S = (const float*)d_in[3];
    float* out = (float*)d_out;

    const int total_rows = in_sizes[0] / NN;   // 131072 = 8192 tiles of 16
    lcgc_kernel<<<dim3(NBLK), dim3(THREADS), 0, stream>>>(
        x, W, b, S, out, total_rows);
}